// Round 6
// baseline (12.585 us; speedup 1.0000x reference)
//
#include <hip/hip_runtime.h>

// E8 attention, closed-form softmax over the E8 root codebook.
//
// Per (token, head), q in R^8, s_r = (q.r)/sqrt(8), p = softmax(s),
// ctx = sum_r p_r r.  Half-exponent form: c = 1/(2 sqrt 8),
//   w_k = exp(c q_k), iw = 1/w, a_k = w+iw, b_k = w-iw,
//   alpha_k = a^2 - 2 (= 2cosh(q/sqrt8)), beta_k = a b (= 2sinh(q/sqrt8)).
// Pair roots (112): numer_i = beta_i (Sa - alpha_i),
//   denom_pair = 0.5 (Sa^2 - sum alpha^2), Sa = sum alpha.
// Half roots (128, even parity), division-free two-family LOO:
//   denom_half = 0.5 (prod a + prod b),
//   numer_k = 0.25 (b_k prod_{m!=k} a_m + a_k prod_{m!=k} b_m).
// 17 transcendental ops/token (8 exp2, 8 rcp, 1 rcp(l)) vs 26 in the
// tanh-form — TRANS is quarter-rate and long-latency, VALU is cheap.
// Exact reformulation; |q| small so f32 exp/rcp are safe (a >= 2).
//
// Layout: 16 lanes per token-group (one per head), T=4 tokens per thread;
// token PAIRS packed into f32x2 so arithmetic runs on v_pk_*_f32.
// Output projection partials reduce-scatter over the 16 head lanes
// (r2-verified mapping; lane h ends owning component j = h>>1).

typedef float f32x2 __attribute__((ext_vector_type(2)));

static constexpr int HEADS = 16;
static constexpr int BN = 8 * 4096;  // tokens
static constexpr int T = 4;          // tokens per thread
static constexpr int P = 2;          // token pairs per thread

__global__ __launch_bounds__(256) void e8_attn_kernel(
    const float* __restrict__ x,
    const float* __restrict__ wq,
    const float* __restrict__ bq,
    const float* __restrict__ wo,
    const float* __restrict__ bo,
    float* __restrict__ out)
{
    const int t = blockIdx.x * 256 + threadIdx.x;
    const int h = t & 15;         // head
    const int tok = (t >> 4) * T; // first token of this thread's group
    const int col = h * 8;

    // ---- x packed across token pairs: xp[pp][i] = {x[2pp][i], x[2pp+1][i]}
    f32x2 xp[P][8];
#pragma unroll
    for (int pp = 0; pp < P; ++pp) {
        const float4 a0 = *(const float4*)(x + (tok + 2 * pp) * 8);
        const float4 b0 = *(const float4*)(x + (tok + 2 * pp) * 8 + 4);
        const float4 a1 = *(const float4*)(x + (tok + 2 * pp + 1) * 8);
        const float4 b1 = *(const float4*)(x + (tok + 2 * pp + 1) * 8 + 4);
        xp[pp][0] = (f32x2){a0.x, a1.x};
        xp[pp][1] = (f32x2){a0.y, a1.y};
        xp[pp][2] = (f32x2){a0.z, a1.z};
        xp[pp][3] = (f32x2){a0.w, a1.w};
        xp[pp][4] = (f32x2){b0.x, b1.x};
        xp[pp][5] = (f32x2){b0.y, b1.y};
        xp[pp][6] = (f32x2){b0.z, b1.z};
        xp[pp][7] = (f32x2){b0.w, b1.w};
    }

    // ---- q = x @ wq + bq, dual accumulators (dep chain 8 -> 4+1) ----
    f32x2 q[P][8];   // first pass: acc0 (bias + i=0..3)
    f32x2 q1[P][8];  // acc1 (i=4..7)
    {
        const float4 c0 = *(const float4*)(bq + col);
        const float4 c1 = *(const float4*)(bq + col + 4);
        const float bqs[8] = {c0.x, c0.y, c0.z, c0.w, c1.x, c1.y, c1.z, c1.w};
#pragma unroll
        for (int k = 0; k < 8; ++k) {
            const f32x2 bb = {bqs[k], bqs[k]};
#pragma unroll
            for (int pp = 0; pp < P; ++pp) {
                q[pp][k] = bb;
                q1[pp][k] = (f32x2){0.f, 0.f};
            }
        }
    }
#pragma unroll
    for (int i = 0; i < 8; ++i) {
        const float4 w0 = *(const float4*)(wq + i * 128 + col);
        const float4 w1 = *(const float4*)(wq + i * 128 + col + 4);
        const float ws[8] = {w0.x, w0.y, w0.z, w0.w, w1.x, w1.y, w1.z, w1.w};
#pragma unroll
        for (int k = 0; k < 8; ++k) {
            const f32x2 wv = {ws[k], ws[k]};
#pragma unroll
            for (int pp = 0; pp < P; ++pp) {
                if (i < 4)
                    q[pp][k] = __builtin_elementwise_fma(xp[pp][i], wv, q[pp][k]);
                else
                    q1[pp][k] = __builtin_elementwise_fma(xp[pp][i], wv, q1[pp][k]);
            }
        }
    }
    // combine + scale so w = exp2(q') = exp(q/(2 sqrt 8))
    const float C = 0.25506807186927930f;  // log2(e) / (2 sqrt 8)
#pragma unroll
    for (int k = 0; k < 8; ++k)
#pragma unroll
        for (int pp = 0; pp < P; ++pp)
            q[pp][k] = (q[pp][k] + q1[pp][k]) * C;

    // ---- hyperbolic blocks (token-pair packed) ----
    f32x2 av[P][8], bv[P][8], Sm[P][8];
    f32x2 Sa[P], Sa2[P], Pa[P], Pb[P];
#pragma unroll
    for (int pp = 0; pp < P; ++pp) {
        Sa[pp]  = (f32x2){0.f, 0.f};
        Sa2[pp] = (f32x2){0.f, 0.f};
        Pa[pp]  = (f32x2){1.f, 1.f};
        Pb[pp]  = (f32x2){1.f, 1.f};
    }
#pragma unroll
    for (int k = 0; k < 8; ++k) {
#pragma unroll
        for (int pp = 0; pp < P; ++pp) {
            f32x2 w, iw;
            w.x  = __builtin_amdgcn_exp2f(q[pp][k].x);
            w.y  = __builtin_amdgcn_exp2f(q[pp][k].y);
            iw.x = __builtin_amdgcn_rcpf(w.x);
            iw.y = __builtin_amdgcn_rcpf(w.y);
            const f32x2 a = w + iw;
            const f32x2 b = w - iw;
            const f32x2 al = __builtin_elementwise_fma(a, a, (f32x2){-2.f, -2.f});
            av[pp][k] = a; bv[pp][k] = b; Sm[pp][k] = al;
            Sa[pp]  = Sa[pp] + al;
            Sa2[pp] = __builtin_elementwise_fma(al, al, Sa2[pp]);
            Pa[pp]  = Pa[pp] * a;
            Pb[pp]  = Pb[pp] * b;
        }
    }
#pragma unroll
    for (int k = 0; k < 8; ++k)
#pragma unroll
        for (int pp = 0; pp < P; ++pp) Sm[pp][k] = Sa[pp] - Sm[pp][k];

    // ---- suffix products (both families); denominator; fold reciprocal ----
    f32x2 sufA[P][8], sufB[P][8], rl[P], rq[P];
#pragma unroll
    for (int pp = 0; pp < P; ++pp) {
        sufA[pp][7] = (f32x2){1.f, 1.f};
        sufB[pp][7] = (f32x2){1.f, 1.f};
#pragma unroll
        for (int k = 6; k >= 0; --k) {
            sufA[pp][k] = sufA[pp][k + 1] * av[pp][k + 1];
            sufB[pp][k] = sufB[pp][k + 1] * bv[pp][k + 1];
        }
        const f32x2 l = 0.5f * __builtin_elementwise_fma(Sa[pp], Sa[pp], -Sa2[pp])
                      + 0.5f * (Pa[pp] + Pb[pp]);
        f32x2 r;
        r.x = __builtin_amdgcn_rcpf(l.x);
        r.y = __builtin_amdgcn_rcpf(l.y);
        rl[pp] = r;
        rq[pp] = 0.25f * r;
    }

    // ---- fused numer + output projection ----
    f32x2 po[T][4];
#pragma unroll
    for (int u = 0; u < T; ++u)
#pragma unroll
        for (int m = 0; m < 4; ++m) po[u][m] = (f32x2){0.f, 0.f};

    f32x2 preA[P], preB[P];
#pragma unroll
    for (int pp = 0; pp < P; ++pp) {
        preA[pp] = (f32x2){1.f, 1.f};
        preB[pp] = (f32x2){1.f, 1.f};
    }

    const float* wo_h = wo + col * 8;
#pragma unroll
    for (int k = 0; k < 8; ++k) {
        const float4 w0 = *(const float4*)(wo_h + k * 8);
        const float4 w1 = *(const float4*)(wo_h + k * 8 + 4);
        const f32x2 wv0 = {w0.x, w0.y}, wv1 = {w0.z, w0.w};
        const f32x2 wv2 = {w1.x, w1.y}, wv3 = {w1.z, w1.w};
#pragma unroll
        for (int pp = 0; pp < P; ++pp) {
            const f32x2 a = av[pp][k], b = bv[pp][k];
            const f32x2 beta   = a * b;
            const f32x2 pairnm = beta * Sm[pp][k];
            const f32x2 Abar   = preA[pp] * sufA[pp][k];
            const f32x2 Bbar   = preB[pp] * sufB[pp][k];
            const f32x2 hm     = __builtin_elementwise_fma(b, Abar, a * Bbar);
            const f32x2 nm     = __builtin_elementwise_fma(pairnm, rl[pp], hm * rq[pp]);
            preA[pp] = preA[pp] * a;
            preB[pp] = preB[pp] * b;
            const f32x2 n0 = {nm.x, nm.x};
            const f32x2 n1 = {nm.y, nm.y};
            po[2*pp][0]   = __builtin_elementwise_fma(n0, wv0, po[2*pp][0]);
            po[2*pp][1]   = __builtin_elementwise_fma(n0, wv1, po[2*pp][1]);
            po[2*pp][2]   = __builtin_elementwise_fma(n0, wv2, po[2*pp][2]);
            po[2*pp][3]   = __builtin_elementwise_fma(n0, wv3, po[2*pp][3]);
            po[2*pp+1][0] = __builtin_elementwise_fma(n1, wv0, po[2*pp+1][0]);
            po[2*pp+1][1] = __builtin_elementwise_fma(n1, wv1, po[2*pp+1][1]);
            po[2*pp+1][2] = __builtin_elementwise_fma(n1, wv2, po[2*pp+1][2]);
            po[2*pp+1][3] = __builtin_elementwise_fma(n1, wv3, po[2*pp+1][3]);
        }
    }

    // ---- reduce-scatter over the 16 head lanes (r2-verified mapping) ----
    const bool h3 = (h & 8) != 0;
    const bool h2 = (h & 4) != 0;
    const bool h1 = (h & 2) != 0;
    float rr[T];
#pragma unroll
    for (int u = 0; u < T; ++u) {
        float po8[8];
#pragma unroll
        for (int j = 0; j < 8; ++j) po8[j] = po[u][j >> 1][j & 1];
        float r4[4];
#pragma unroll
        for (int m = 0; m < 4; ++m) {
            const float send = h3 ? po8[m] : po8[4 + m];
            const float keep = h3 ? po8[4 + m] : po8[m];
            r4[m] = keep + __shfl_xor(send, 8, 64);
        }
        float r2v[2];
#pragma unroll
        for (int m = 0; m < 2; ++m) {
            const float send = h2 ? r4[m] : r4[2 + m];
            const float keep = h2 ? r4[2 + m] : r4[m];
            r2v[m] = keep + __shfl_xor(send, 4, 64);
        }
        {
            const float send = h1 ? r2v[0] : r2v[1];
            const float keep = h1 ? r2v[1] : r2v[0];
            rr[u] = keep + __shfl_xor(send, 2, 64);
        }
        rr[u] += __shfl_xor(rr[u], 1, 64);
    }

    // lane h (h even) owns output component j = h>>1 for its T tokens
    if ((h & 1) == 0) {
        const int j = h >> 1;
        const float boj = bo[j];
#pragma unroll
        for (int u = 0; u < T; ++u)
            out[(tok + u) * 8 + j] = rr[u] + boj;
    }
}

extern "C" void kernel_launch(void* const* d_in, const int* in_sizes, int n_in,
                              void* d_out, int out_size, void* d_ws, size_t ws_size,
                              hipStream_t stream) {
    const float* x  = (const float*)d_in[0];
    const float* wq = (const float*)d_in[1];
    const float* bq = (const float*)d_in[2];
    // d_in[3..6] = wk, bk, wv, bv: dead code in the reference
    const float* wo = (const float*)d_in[7];
    const float* bo = (const float*)d_in[8];
    float* out = (float*)d_out;

    const int threads = (BN / T) * HEADS;   // 131072 -> 512 blocks x 256
    e8_attn_kernel<<<threads / 256, 256, 0, stream>>>(x, wq, bq, wo, bo, out);
}

// Round 7
// 12.390 us; speedup vs baseline: 1.0158x; 1.0158x over previous
//
#include <hip/hip_runtime.h>

// E8 attention, closed-form softmax over the E8 root codebook.
//
// Per (token, head), q in R^8, s_r = (q.r)/sqrt(8), p = softmax(s),
// ctx = sum_r p_r r.  Half-exponent tanh form: c = 1/(2 sqrt 8),
//   w = exp(c q_k), iw = exp(-c q_k)   (two independent exp2 ops),
//   a = w + iw (>= 2), b = w - iw, t = b * rcp(a) = tanh(c q_k),
//   alpha = a^2 - 2 (= 2cosh(q/sqrt8)), a*b = (alpha+2) t (= 2sinh(q/sqrt8)).
// Pair roots (112): numer_i = (alpha_i+2) t_i (Sa - alpha_i),
//   denom_pair = 0.5 (Sa^2 - sum alpha^2), Sa = sum alpha.
// Half roots (128, even parity), single-family LOO over t:
//   denom_half = 0.5 Pa (1 + prod t),  Pa = prod a,
//   numer_k = 0.25 Pa (t_k + prod_{m!=k} t_m)  via preT/sufT suffix products.
// Exact reformulation (r4-verified algebra); |q| small so f32 exp/rcp safe.
//
// Layout: 16 lanes per token-group (one per head), T=4 tokens per thread;
// token PAIRS packed into f32x2 so arithmetic runs on v_pk_*_f32; only
// exp2/rcp are scalar (TRANS has no packed form). Live register arrays
// kept to 3x16 f32x2 (alpha, t, sufT) to stay spill-free.
// Output projection partials reduce-scatter over the 16 head lanes
// (r2-verified mapping; lane h ends owning component j = h>>1).

typedef float f32x2 __attribute__((ext_vector_type(2)));

static constexpr int HEADS = 16;
static constexpr int BN = 8 * 4096;  // tokens
static constexpr int T = 4;          // tokens per thread
static constexpr int P = 2;          // token pairs per thread

__global__ __launch_bounds__(256) void e8_attn_kernel(
    const float* __restrict__ x,
    const float* __restrict__ wq,
    const float* __restrict__ bq,
    const float* __restrict__ wo,
    const float* __restrict__ bo,
    float* __restrict__ out)
{
    const int t = blockIdx.x * 256 + threadIdx.x;
    const int h = t & 15;         // head
    const int tok = (t >> 4) * T; // first token of this thread's group
    const int col = h * 8;

    // ---- x packed across token pairs: xp[pp][i] = {x[2pp][i], x[2pp+1][i]}
    f32x2 xp[P][8];
#pragma unroll
    for (int pp = 0; pp < P; ++pp) {
        const float4 a0 = *(const float4*)(x + (tok + 2 * pp) * 8);
        const float4 b0 = *(const float4*)(x + (tok + 2 * pp) * 8 + 4);
        const float4 a1 = *(const float4*)(x + (tok + 2 * pp + 1) * 8);
        const float4 b1 = *(const float4*)(x + (tok + 2 * pp + 1) * 8 + 4);
        xp[pp][0] = (f32x2){a0.x, a1.x};
        xp[pp][1] = (f32x2){a0.y, a1.y};
        xp[pp][2] = (f32x2){a0.z, a1.z};
        xp[pp][3] = (f32x2){a0.w, a1.w};
        xp[pp][4] = (f32x2){b0.x, b1.x};
        xp[pp][5] = (f32x2){b0.y, b1.y};
        xp[pp][6] = (f32x2){b0.z, b1.z};
        xp[pp][7] = (f32x2){b0.w, b1.w};
    }

    // ---- q = x @ wq + bq for my head, token-pair packed ----
    f32x2 q[P][8];
    {
        const float4 c0 = *(const float4*)(bq + col);
        const float4 c1 = *(const float4*)(bq + col + 4);
        const float bqs[8] = {c0.x, c0.y, c0.z, c0.w, c1.x, c1.y, c1.z, c1.w};
#pragma unroll
        for (int k = 0; k < 8; ++k) {
            const f32x2 bb = {bqs[k], bqs[k]};
#pragma unroll
            for (int pp = 0; pp < P; ++pp) q[pp][k] = bb;
        }
    }
#pragma unroll
    for (int i = 0; i < 8; ++i) {
        const float4 w0 = *(const float4*)(wq + i * 128 + col);
        const float4 w1 = *(const float4*)(wq + i * 128 + col + 4);
        const float ws[8] = {w0.x, w0.y, w0.z, w0.w, w1.x, w1.y, w1.z, w1.w};
#pragma unroll
        for (int k = 0; k < 8; ++k) {
            const f32x2 wv = {ws[k], ws[k]};
#pragma unroll
            for (int pp = 0; pp < P; ++pp)
                q[pp][k] = __builtin_elementwise_fma(xp[pp][i], wv, q[pp][k]);
        }
    }

    // ---- scale so w = exp2(qs) = exp(q/(2 sqrt 8)) ----
    const float C = 0.25506807186927930f;  // log2(e) / (2 sqrt 8)
#pragma unroll
    for (int k = 0; k < 8; ++k)
#pragma unroll
        for (int pp = 0; pp < P; ++pp) q[pp][k] = q[pp][k] * C;

    // ---- hyperbolic blocks (token-pair packed) ----
    f32x2 alv[P][8], tkv[P][8];
    f32x2 Sa[P], Sa2[P], Pa[P];
#pragma unroll
    for (int pp = 0; pp < P; ++pp) {
        Sa[pp]  = (f32x2){0.f, 0.f};
        Sa2[pp] = (f32x2){0.f, 0.f};
        Pa[pp]  = (f32x2){1.f, 1.f};
    }
#pragma unroll
    for (int k = 0; k < 8; ++k) {
#pragma unroll
        for (int pp = 0; pp < P; ++pp) {
            const f32x2 qs = q[pp][k];
            f32x2 w, iw, ra;
            w.x  = __builtin_amdgcn_exp2f(qs.x);   // independent pair:
            w.y  = __builtin_amdgcn_exp2f(qs.y);
            iw.x = __builtin_amdgcn_exp2f(-qs.x);  // neg folds into VOP3 mod
            iw.y = __builtin_amdgcn_exp2f(-qs.y);
            const f32x2 a = w + iw;
            const f32x2 b = w - iw;
            ra.x = __builtin_amdgcn_rcpf(a.x);
            ra.y = __builtin_amdgcn_rcpf(a.y);
            const f32x2 tk = b * ra;
            const f32x2 al = __builtin_elementwise_fma(a, a, (f32x2){-2.f, -2.f});
            alv[pp][k] = al;
            tkv[pp][k] = tk;
            Sa[pp]  = Sa[pp] + al;
            Sa2[pp] = __builtin_elementwise_fma(al, al, Sa2[pp]);
            Pa[pp]  = Pa[pp] * a;
        }
    }

    // ---- suffix products of t; denominator; fold reciprocal ----
    f32x2 sufT[P][8], rl[P], qPa[P];
#pragma unroll
    for (int pp = 0; pp < P; ++pp) {
        sufT[pp][7] = (f32x2){1.f, 1.f};
#pragma unroll
        for (int k = 6; k >= 0; --k)
            sufT[pp][k] = sufT[pp][k + 1] * tkv[pp][k + 1];
        const f32x2 PT = sufT[pp][0] * tkv[pp][0];
        const f32x2 u  = __builtin_elementwise_fma(Sa[pp], Sa[pp], -Sa2[pp]);
        const f32x2 v  = __builtin_elementwise_fma(Pa[pp], PT, Pa[pp]);
        const f32x2 l  = 0.5f * (u + v);
        f32x2 r;
        r.x = __builtin_amdgcn_rcpf(l.x);
        r.y = __builtin_amdgcn_rcpf(l.y);
        rl[pp]  = r;
        qPa[pp] = (0.25f * Pa[pp]) * r;
    }

    // ---- fused numer + output projection ----
    f32x2 po[T][4];
#pragma unroll
    for (int u = 0; u < T; ++u)
#pragma unroll
        for (int m = 0; m < 4; ++m) po[u][m] = (f32x2){0.f, 0.f};

    f32x2 preT[P];
#pragma unroll
    for (int pp = 0; pp < P; ++pp) preT[pp] = (f32x2){1.f, 1.f};

    const float* wo_h = wo + col * 8;
#pragma unroll
    for (int k = 0; k < 8; ++k) {
        const float4 w0 = *(const float4*)(wo_h + k * 8);
        const float4 w1 = *(const float4*)(wo_h + k * 8 + 4);
        const f32x2 wv0 = {w0.x, w0.y}, wv1 = {w0.z, w0.w};
        const f32x2 wv2 = {w1.x, w1.y}, wv3 = {w1.z, w1.w};
#pragma unroll
        for (int pp = 0; pp < P; ++pp) {
            const f32x2 al = alv[pp][k], tk = tkv[pp][k];
            const f32x2 sm   = Sa[pp] - al;
            const f32x2 ap2  = al + 2.0f;
            const f32x2 pair = (ap2 * tk) * sm;
            const f32x2 loo  = preT[pp] * sufT[pp][k];
            const f32x2 tkl  = tk + loo;
            const f32x2 nm   = __builtin_elementwise_fma(pair, rl[pp], qPa[pp] * tkl);
            preT[pp] = preT[pp] * tk;
            const f32x2 n0 = {nm.x, nm.x};
            const f32x2 n1 = {nm.y, nm.y};
            po[2*pp][0]   = __builtin_elementwise_fma(n0, wv0, po[2*pp][0]);
            po[2*pp][1]   = __builtin_elementwise_fma(n0, wv1, po[2*pp][1]);
            po[2*pp][2]   = __builtin_elementwise_fma(n0, wv2, po[2*pp][2]);
            po[2*pp][3]   = __builtin_elementwise_fma(n0, wv3, po[2*pp][3]);
            po[2*pp+1][0] = __builtin_elementwise_fma(n1, wv0, po[2*pp+1][0]);
            po[2*pp+1][1] = __builtin_elementwise_fma(n1, wv1, po[2*pp+1][1]);
            po[2*pp+1][2] = __builtin_elementwise_fma(n1, wv2, po[2*pp+1][2]);
            po[2*pp+1][3] = __builtin_elementwise_fma(n1, wv3, po[2*pp+1][3]);
        }
    }

    // ---- reduce-scatter over the 16 head lanes (r2-verified mapping) ----
    const bool h3 = (h & 8) != 0;
    const bool h2 = (h & 4) != 0;
    const bool h1 = (h & 2) != 0;
    float rr[T];
#pragma unroll
    for (int u = 0; u < T; ++u) {
        float po8[8];
#pragma unroll
        for (int j = 0; j < 8; ++j) po8[j] = po[u][j >> 1][j & 1];
        float r4[4];
#pragma unroll
        for (int m = 0; m < 4; ++m) {
            const float send = h3 ? po8[m] : po8[4 + m];
            const float keep = h3 ? po8[4 + m] : po8[m];
            r4[m] = keep + __shfl_xor(send, 8, 64);
        }
        float r2v[2];
#pragma unroll
        for (int m = 0; m < 2; ++m) {
            const float send = h2 ? r4[m] : r4[2 + m];
            const float keep = h2 ? r4[2 + m] : r4[m];
            r2v[m] = keep + __shfl_xor(send, 4, 64);
        }
        {
            const float send = h1 ? r2v[0] : r2v[1];
            const float keep = h1 ? r2v[1] : r2v[0];
            rr[u] = keep + __shfl_xor(send, 2, 64);
        }
        rr[u] += __shfl_xor(rr[u], 1, 64);
    }

    // lane h (h even) owns output component j = h>>1 for its T tokens
    if ((h & 1) == 0) {
        const int j = h >> 1;
        const float boj = bo[j];
#pragma unroll
        for (int u = 0; u < T; ++u)
            out[(tok + u) * 8 + j] = rr[u] + boj;
    }
}

extern "C" void kernel_launch(void* const* d_in, const int* in_sizes, int n_in,
                              void* d_out, int out_size, void* d_ws, size_t ws_size,
                              hipStream_t stream) {
    const float* x  = (const float*)d_in[0];
    const float* wq = (const float*)d_in[1];
    const float* bq = (const float*)d_in[2];
    // d_in[3..6] = wk, bk, wv, bv: dead code in the reference
    const float* wo = (const float*)d_in[7];
    const float* bo = (const float*)d_in[8];
    float* out = (float*)d_out;

    const int threads = (BN / T) * HEADS;   // 131072 -> 512 blocks x 256
    e8_attn_kernel<<<threads / 256, 256, 0, stream>>>(x, wq, bq, wo, bo, out);
}

// Round 8
// 12.229 us; speedup vs baseline: 1.0291x; 1.0131x over previous
//
#include <hip/hip_runtime.h>

// E8 attention, closed-form softmax over the E8 root codebook.
// (r5 kernel — measured best at 11.93 us; r6/r7 variants both regressed.)
//
// Per (token, head), q in R^8, s_r = (q.r)/sqrt(8), p = softmax(s),
// ctx = sum_r p_r r.  W-form: W_k = exp(q_k/sqrt8),
//   alpha_k = W + 1/W  (= 2cosh(q/sqrt8))
//   beta_k  = W - 1/W  (= 2sinh(q/sqrt8))
//   t_k     = beta/(alpha+2) = (W-1)/(W+1) = tanh(q/(2 sqrt8))
//   a_k^2   = alpha+2  =>  Pa = prod a_k = sqrt(prod(alpha_k+2))
// Pair roots (112): numer_i = beta_i (Sa - alpha_i),
//   denom_pair = 0.5 (Sa^2 - sum alpha^2),  Sa = sum alpha.
// Half roots (128, even parity): denom_half = 0.5 Pa (1 + prod t),
//   numer_k = 0.25 Pa (t_k + prod_{m!=k} t_m)   (LOO over t via suffix prods).
// Exact reformulation; |q| small so f32 exp/sqrt/rcp are all safe.
//
// Layout: 16 lanes per token-group (one per head), T=4 tokens per thread.
// Token PAIRS are packed into f32x2 so hyper/suffix/denom/numer arithmetic
// runs on v_pk_*_f32 (2 tokens per instruction); exp/rcp/sqrt stay scalar.
// Output projection partials reduce-scatter over the 16 head lanes
// (r2-verified mapping; lane h ends owning component j = h>>1).

typedef float f32x2 __attribute__((ext_vector_type(2)));

static constexpr int HEADS = 16;
static constexpr int BN = 8 * 4096;  // tokens
static constexpr int T = 4;          // tokens per thread
static constexpr int P = 2;          // token pairs per thread

__global__ __launch_bounds__(256) void e8_attn_kernel(
    const float* __restrict__ x,
    const float* __restrict__ wq,
    const float* __restrict__ bq,
    const float* __restrict__ wo,
    const float* __restrict__ bo,
    float* __restrict__ out)
{
    const int t = blockIdx.x * 256 + threadIdx.x;
    const int h = t & 15;         // head
    const int tok = (t >> 4) * T; // first token of this thread's group
    const int col = h * 8;

    // ---- x packed across token pairs: xp[pp][i] = {x[2pp][i], x[2pp+1][i]}
    f32x2 xp[P][8];
#pragma unroll
    for (int pp = 0; pp < P; ++pp) {
        const float4 a0 = *(const float4*)(x + (tok + 2 * pp) * 8);
        const float4 b0 = *(const float4*)(x + (tok + 2 * pp) * 8 + 4);
        const float4 a1 = *(const float4*)(x + (tok + 2 * pp + 1) * 8);
        const float4 b1 = *(const float4*)(x + (tok + 2 * pp + 1) * 8 + 4);
        xp[pp][0] = (f32x2){a0.x, a1.x};
        xp[pp][1] = (f32x2){a0.y, a1.y};
        xp[pp][2] = (f32x2){a0.z, a1.z};
        xp[pp][3] = (f32x2){a0.w, a1.w};
        xp[pp][4] = (f32x2){b0.x, b1.x};
        xp[pp][5] = (f32x2){b0.y, b1.y};
        xp[pp][6] = (f32x2){b0.z, b1.z};
        xp[pp][7] = (f32x2){b0.w, b1.w};
    }

    // ---- q = x @ wq + bq for my head, token-pair packed ----
    f32x2 q[P][8];
    {
        const float4 c0 = *(const float4*)(bq + col);
        const float4 c1 = *(const float4*)(bq + col + 4);
        const float bqs[8] = {c0.x, c0.y, c0.z, c0.w, c1.x, c1.y, c1.z, c1.w};
#pragma unroll
        for (int k = 0; k < 8; ++k) {
            const f32x2 bb = {bqs[k], bqs[k]};
#pragma unroll
            for (int pp = 0; pp < P; ++pp) q[pp][k] = bb;
        }
    }
#pragma unroll
    for (int i = 0; i < 8; ++i) {
        const float4 w0 = *(const float4*)(wq + i * 128 + col);
        const float4 w1 = *(const float4*)(wq + i * 128 + col + 4);
        const float ws[8] = {w0.x, w0.y, w0.z, w0.w, w1.x, w1.y, w1.z, w1.w};
#pragma unroll
        for (int k = 0; k < 8; ++k) {
            const f32x2 wv = {ws[k], ws[k]};
#pragma unroll
            for (int pp = 0; pp < P; ++pp)
                q[pp][k] = __builtin_elementwise_fma(xp[pp][i], wv, q[pp][k]);
        }
    }

    // ---- scale so W = exp2(q') = exp(q/sqrt8) ----
    const float CW = 0.51006973f;  // log2(e)/sqrt(8)
#pragma unroll
    for (int k = 0; k < 8; ++k)
#pragma unroll
        for (int pp = 0; pp < P; ++pp) q[pp][k] = q[pp][k] * CW;

    // ---- hyperbolic blocks (token-pair packed) ----
    f32x2 Sm[P][8], beta[P][8], tkv[P][8];
    f32x2 Sa[P], Sa2[P], P2[P];
#pragma unroll
    for (int pp = 0; pp < P; ++pp) {
        Sa[pp]  = (f32x2){0.f, 0.f};
        Sa2[pp] = (f32x2){0.f, 0.f};
        P2[pp]  = (f32x2){1.f, 1.f};
    }
#pragma unroll
    for (int k = 0; k < 8; ++k) {
#pragma unroll
        for (int pp = 0; pp < P; ++pp) {
            f32x2 W, iW, rd;
            W.x  = __builtin_amdgcn_exp2f(q[pp][k].x);
            W.y  = __builtin_amdgcn_exp2f(q[pp][k].y);
            iW.x = __builtin_amdgcn_rcpf(W.x);
            iW.y = __builtin_amdgcn_rcpf(W.y);
            const f32x2 al = W + iW;
            const f32x2 be = W - iW;
            const f32x2 d  = al + 2.0f;
            rd.x = __builtin_amdgcn_rcpf(d.x);
            rd.y = __builtin_amdgcn_rcpf(d.y);
            beta[pp][k] = be;
            tkv[pp][k]  = be * rd;
            Sm[pp][k]   = al;  // alpha for now; becomes Sa - alpha below
            Sa[pp]  = Sa[pp] + al;
            Sa2[pp] = __builtin_elementwise_fma(al, al, Sa2[pp]);
            P2[pp]  = P2[pp] * d;
        }
    }
#pragma unroll
    for (int k = 0; k < 8; ++k)
#pragma unroll
        for (int pp = 0; pp < P; ++pp) Sm[pp][k] = Sa[pp] - Sm[pp][k];

    // ---- suffix products of t; denominator; fold reciprocal ----
    f32x2 sufT[P][8], rl[P], qPa[P];
#pragma unroll
    for (int pp = 0; pp < P; ++pp) {
        sufT[pp][7] = (f32x2){1.f, 1.f};
#pragma unroll
        for (int k = 6; k >= 0; --k)
            sufT[pp][k] = sufT[pp][k + 1] * tkv[pp][k + 1];
        const f32x2 PT = sufT[pp][0] * tkv[pp][0];
        f32x2 Pa;
        Pa.x = __builtin_amdgcn_sqrtf(P2[pp].x);
        Pa.y = __builtin_amdgcn_sqrtf(P2[pp].y);
        const f32x2 l = 0.5f * __builtin_elementwise_fma(Sa[pp], Sa[pp], -Sa2[pp])
                      + (0.5f * Pa) * (PT + 1.0f);
        f32x2 r;
        r.x = __builtin_amdgcn_rcpf(l.x);
        r.y = __builtin_amdgcn_rcpf(l.y);
        rl[pp]  = r;
        qPa[pp] = (0.25f * Pa) * r;
    }

    // ---- fused numer + output projection ----
    f32x2 po[T][4];
#pragma unroll
    for (int u = 0; u < T; ++u)
#pragma unroll
        for (int m = 0; m < 4; ++m) po[u][m] = (f32x2){0.f, 0.f};

    f32x2 preT[P];
#pragma unroll
    for (int pp = 0; pp < P; ++pp) preT[pp] = (f32x2){1.f, 1.f};

    const float* wo_h = wo + col * 8;
#pragma unroll
    for (int k = 0; k < 8; ++k) {
        const float4 w0 = *(const float4*)(wo_h + k * 8);
        const float4 w1 = *(const float4*)(wo_h + k * 8 + 4);
        const f32x2 wv0 = {w0.x, w0.y}, wv1 = {w0.z, w0.w};
        const f32x2 wv2 = {w1.x, w1.y}, wv3 = {w1.z, w1.w};
#pragma unroll
        for (int pp = 0; pp < P; ++pp) {
            const f32x2 pairnm = beta[pp][k] * Sm[pp][k];
            const f32x2 loo    = preT[pp] * sufT[pp][k];
            const f32x2 tkl    = tkv[pp][k] + loo;
            const f32x2 nm     = __builtin_elementwise_fma(pairnm, rl[pp], qPa[pp] * tkl);
            preT[pp] = preT[pp] * tkv[pp][k];
            const f32x2 n0 = {nm.x, nm.x};
            const f32x2 n1 = {nm.y, nm.y};
            po[2*pp][0]   = __builtin_elementwise_fma(n0, wv0, po[2*pp][0]);
            po[2*pp][1]   = __builtin_elementwise_fma(n0, wv1, po[2*pp][1]);
            po[2*pp][2]   = __builtin_elementwise_fma(n0, wv2, po[2*pp][2]);
            po[2*pp][3]   = __builtin_elementwise_fma(n0, wv3, po[2*pp][3]);
            po[2*pp+1][0] = __builtin_elementwise_fma(n1, wv0, po[2*pp+1][0]);
            po[2*pp+1][1] = __builtin_elementwise_fma(n1, wv1, po[2*pp+1][1]);
            po[2*pp+1][2] = __builtin_elementwise_fma(n1, wv2, po[2*pp+1][2]);
            po[2*pp+1][3] = __builtin_elementwise_fma(n1, wv3, po[2*pp+1][3]);
        }
    }

    // ---- reduce-scatter over the 16 head lanes (r2-verified mapping) ----
    const bool h3 = (h & 8) != 0;
    const bool h2 = (h & 4) != 0;
    const bool h1 = (h & 2) != 0;
    float rr[T];
#pragma unroll
    for (int u = 0; u < T; ++u) {
        float po8[8];
#pragma unroll
        for (int j = 0; j < 8; ++j) po8[j] = po[u][j >> 1][j & 1];
        float r4[4];
#pragma unroll
        for (int m = 0; m < 4; ++m) {
            const float send = h3 ? po8[m] : po8[4 + m];
            const float keep = h3 ? po8[4 + m] : po8[m];
            r4[m] = keep + __shfl_xor(send, 8, 64);
        }
        float r2v[2];
#pragma unroll
        for (int m = 0; m < 2; ++m) {
            const float send = h2 ? r4[m] : r4[2 + m];
            const float keep = h2 ? r4[2 + m] : r4[m];
            r2v[m] = keep + __shfl_xor(send, 4, 64);
        }
        {
            const float send = h1 ? r2v[0] : r2v[1];
            const float keep = h1 ? r2v[1] : r2v[0];
            rr[u] = keep + __shfl_xor(send, 2, 64);
        }
        rr[u] += __shfl_xor(rr[u], 1, 64);
    }

    // lane h (h even) owns output component j = h>>1 for its T tokens
    if ((h & 1) == 0) {
        const int j = h >> 1;
        const float boj = bo[j];
#pragma unroll
        for (int u = 0; u < T; ++u)
            out[(tok + u) * 8 + j] = rr[u] + boj;
    }
}

extern "C" void kernel_launch(void* const* d_in, const int* in_sizes, int n_in,
                              void* d_out, int out_size, void* d_ws, size_t ws_size,
                              hipStream_t stream) {
    const float* x  = (const float*)d_in[0];
    const float* wq = (const float*)d_in[1];
    const float* bq = (const float*)d_in[2];
    // d_in[3..6] = wk, bk, wv, bv: dead code in the reference
    const float* wo = (const float*)d_in[7];
    const float* bo = (const float*)d_in[8];
    float* out = (float*)d_out;

    const int threads = (BN / T) * HEADS;   // 131072 -> 512 blocks x 256
    e8_attn_kernel<<<threads / 256, 256, 0, stream>>>(x, wq, bq, wo, bo, out);
}